// Round 10
// baseline (177.526 us; speedup 1.0000x reference)
//
#include <hip/hip_runtime.h>
#include <hip/hip_bf16.h>
#include <hip/hip_cooperative_groups.h>

// N=2, L=8192, dim=256, H=8, Pd=32. seg = n*8+h (16 segs of 8192 rows).
// R10: COOPERATIVE FUSION — k_scan folded into k_gemm (R8 PMC: k_scan 10.6us,
//   30% HBM, 10.7% occupancy, mostly re-reading pk/c/cd that k_gemm still
//   holds in LDS). Grid 256 (=1 block/CU @110KB LDS, co-resident), launched
//   via hipLaunchCooperativeKernel.
//   Phase A (= R9 k_gemm): stage Y/X, register-prefetch B k-loop (no
//     barriers), phi, dpq chain, c/cd -> LDS scc/scd, tile totals -> global
//     tot (NEW: interleaved {num,den} float2 per d), pk -> LDS spk only.
//     pk/c/cd global stores DELETED (8+1 MB writes gone).
//   grid.sync()
//   Phase B: per-block scan of its own 64 rows from LDS. Prefix over tot:
//     half-range per half-lane + shfl_xor(32) combine, 8-deep float2 ILP;
//     g=1 walkers add own tile0 total. 512 walkers x 32 serial steps,
//     out stores NT, fully coalesced (1KB rows across 8 waves).
// ws floats: Wf[bf16 196608]=98304 | tot 16*256*64 = 262144  (~1.4 MB)

namespace cg = cooperative_groups;

typedef __attribute__((ext_vector_type(8))) short short8;  // 8 bf16
typedef __attribute__((ext_vector_type(4))) float f32x4;

__device__ __forceinline__ float phi_f(float x) {
    return x > 0.f ? x + 1.f : __expf(x);   // elu(x)+1
}
__device__ __forceinline__ unsigned short f2bf(float x) {
    __hip_bfloat16 h = __float2bfloat16(x);   // RNE
    return *reinterpret_cast<unsigned short*>(&h);
}
__device__ __forceinline__ float bf2f(unsigned short u) {
    return __uint_as_float(((unsigned int)u) << 16);
}

// ---------------- K1: W -> bf16 fragment order ----------------------------
__global__ __launch_bounds__(256) void k_prepw(
        const float* __restrict__ Wq, const float* __restrict__ Wk,
        const float* __restrict__ Wv, unsigned short* __restrict__ Wf)
{
    const int g = blockIdx.x * 256 + threadIdx.x;   // 0..24575
    const int mat = g >> 13, cc = g & 8191;         // 0=q, 1=v, 2=k
    const float* src = (mat == 0) ? Wq : (mat == 1 ? Wv : Wk);
    const int ln = cc & 15, qd = (cc >> 4) & 3, kt = (cc >> 6) & 7, jt = cc >> 9;
    const float* s = src + (size_t)(jt * 16 + ln) * 256 + kt * 32 + qd * 8;
    f32x4 f0 = __builtin_nontemporal_load((const f32x4*)s);
    f32x4 f1 = __builtin_nontemporal_load((const f32x4*)(s + 4));
    short8 o;
    o[0] = f2bf(f0[0]); o[1] = f2bf(f0[1]); o[2] = f2bf(f0[2]); o[3] = f2bf(f0[3]);
    o[4] = f2bf(f1[0]); o[5] = f2bf(f1[1]); o[6] = f2bf(f1[2]); o[7] = f2bf(f1[3]);
    *(short8*)(Wf + (size_t)g * 8) = o;   // temporal: L2/L3-resident for k_gemm
}

// ---------------- K2: fused GEMM + scan (cooperative) ---------------------
#define LDA 280   // shorts/row: 140 dwords == 12 mod 32 -> 2-way max (free)

__global__ __launch_bounds__(512, 2) void k_gemm(
        const float* __restrict__ Y, const float* __restrict__ X,
        const unsigned short* __restrict__ Wf,
        float* __restrict__ tot, float* __restrict__ out)
{
    __shared__ __align__(16) unsigned short Ys[65 * LDA];   // 36.4 KB (+1 boundary)
    __shared__ __align__(16) unsigned short Xs[64 * LDA];   // 35.8 KB
    __shared__ float scc[64][8], scd[64][8];                //  4.0 KB
    __shared__ __align__(16) unsigned short spk[64 * 264];  // 33.8 KB  (~110KB total)

    const int rb = blockIdx.x;            // rows 64rb..64rb+63
    const int n = rb >> 7, tpair = rb & 127;
    const int mbase = rb * 64;
    const int tile0 = tpair * 2, lseg0 = tpair * 64;
    const bool hasprev = (tpair != 0);
    const int t = threadIdx.x, w = t >> 6, lane = t & 63;   // wave w = head w
    const int ln = lane & 15, qd = lane >> 4;

    // ---- A staging: Y+X 64-row tiles, coalesced NT loads -> bf16 LDS ----
#pragma unroll
    for (int it = 0; it < 16; ++it) {
        const int idx = t + it * 512;                 // 0..8191
        const int half = idx >> 12, row = (idx >> 6) & 63, c4 = idx & 63;
        const float* s = (half ? X : Y) + (size_t)(mbase + row) * 256 + c4 * 4;
        f32x4 f = __builtin_nontemporal_load((const f32x4*)s);
        ushort4 h4;
        h4.x = f2bf(f[0]); h4.y = f2bf(f[1]); h4.z = f2bf(f[2]); h4.w = f2bf(f[3]);
        unsigned short* dst = half ? Xs : Ys;
        *(ushort4*)&dst[row * LDA + c4 * 4] = h4;
    }
    if (t < 64) {                                     // boundary row mbase-1
        const int prow = hasprev ? mbase - 1 : mbase; // clamped; masked later
        f32x4 f = __builtin_nontemporal_load((const f32x4*)(Y + (size_t)prow * 256 + t * 4));
        ushort4 h4;
        h4.x = f2bf(f[0]); h4.y = f2bf(f[1]); h4.z = f2bf(f[2]); h4.w = f2bf(f[3]);
        *(ushort4*)&Ys[64 * LDA + t * 4] = h4;
    }
    __syncthreads();

    // ---- accumulators: [tile][rowhalf][jj] ----
    f32x4 aq[2][2][2], av[2][2][2], akk[2][2][2], aqp[2];
#pragma unroll
    for (int t2 = 0; t2 < 2; ++t2)
#pragma unroll
        for (int i = 0; i < 2; ++i)
#pragma unroll
            for (int j = 0; j < 2; ++j) {
                aq[t2][i][j]  = (f32x4){0.f, 0.f, 0.f, 0.f};
                av[t2][i][j]  = (f32x4){0.f, 0.f, 0.f, 0.f};
                akk[t2][i][j] = (f32x4){0.f, 0.f, 0.f, 0.f};
            }
    aqp[0] = (f32x4){0.f, 0.f, 0.f, 0.f};
    aqp[1] = (f32x4){0.f, 0.f, 0.f, 0.f};
    const short8 z8 = {0, 0, 0, 0, 0, 0, 0, 0};
    const short8* W8 = (const short8*)Wf;
    const int jt0 = 2 * w;

    // ---- B-fragment register prefetch: 3 rotating slots, kt+2 ahead ----
    short8 Bq[3][2], Bv[3][2], Bk[3][2];
#define LOADB(slot, kt_)                                                   \
    {                                                                      \
        _Pragma("unroll")                                                  \
        for (int jj = 0; jj < 2; ++jj) {                                   \
            const int jt = jt0 + jj;                                       \
            Bq[slot][jj] = W8[(((0 * 16 + jt) * 8 + (kt_)) << 6) + lane];  \
            Bv[slot][jj] = W8[(((1 * 16 + jt) * 8 + (kt_)) << 6) + lane];  \
            Bk[slot][jj] = W8[(((2 * 16 + jt) * 8 + (kt_)) << 6) + lane];  \
        }                                                                  \
    }
    LOADB(0, 0);
    LOADB(1, 1);

#pragma unroll
    for (int kt = 0; kt < 8; ++kt) {
        if (kt + 2 < 8) LOADB((kt + 2) % 3, kt + 2);   // constant after unroll
        const int ko = kt * 32 + qd * 8;
        short8 ay[2][2], ax[2][2];
#pragma unroll
        for (int t2 = 0; t2 < 2; ++t2)
#pragma unroll
            for (int i = 0; i < 2; ++i) {
                ay[t2][i] = *(const short8*)&Ys[(t2 * 32 + i * 16 + ln) * LDA + ko];
                ax[t2][i] = *(const short8*)&Xs[(t2 * 32 + i * 16 + ln) * LDA + ko];
            }
        short8 ext = *(const short8*)&Ys[64 * LDA + ko];   // broadcast read
        short8 ayp = (ln == 15) ? ext : z8;                // masked A-frag
        const int sl = kt % 3;
#pragma unroll
        for (int jj = 0; jj < 2; ++jj) {
            aq[0][0][jj] = __builtin_amdgcn_mfma_f32_16x16x32_bf16(ay[0][0], Bq[sl][jj], aq[0][0][jj], 0, 0, 0);
            aq[0][1][jj] = __builtin_amdgcn_mfma_f32_16x16x32_bf16(ay[0][1], Bq[sl][jj], aq[0][1][jj], 0, 0, 0);
            aq[1][0][jj] = __builtin_amdgcn_mfma_f32_16x16x32_bf16(ay[1][0], Bq[sl][jj], aq[1][0][jj], 0, 0, 0);
            aq[1][1][jj] = __builtin_amdgcn_mfma_f32_16x16x32_bf16(ay[1][1], Bq[sl][jj], aq[1][1][jj], 0, 0, 0);
            aqp[jj]      = __builtin_amdgcn_mfma_f32_16x16x32_bf16(ayp,      Bq[sl][jj], aqp[jj],      0, 0, 0);
            av[0][0][jj] = __builtin_amdgcn_mfma_f32_16x16x32_bf16(ax[0][0], Bv[sl][jj], av[0][0][jj], 0, 0, 0);
            av[0][1][jj] = __builtin_amdgcn_mfma_f32_16x16x32_bf16(ax[0][1], Bv[sl][jj], av[0][1][jj], 0, 0, 0);
            av[1][0][jj] = __builtin_amdgcn_mfma_f32_16x16x32_bf16(ax[1][0], Bv[sl][jj], av[1][0][jj], 0, 0, 0);
            av[1][1][jj] = __builtin_amdgcn_mfma_f32_16x16x32_bf16(ax[1][1], Bv[sl][jj], av[1][1][jj], 0, 0, 0);
            akk[0][0][jj] = __builtin_amdgcn_mfma_f32_16x16x32_bf16(ax[0][0], Bk[sl][jj], akk[0][0][jj], 0, 0, 0);
            akk[0][1][jj] = __builtin_amdgcn_mfma_f32_16x16x32_bf16(ax[0][1], Bk[sl][jj], akk[0][1][jj], 0, 0, 0);
            akk[1][0][jj] = __builtin_amdgcn_mfma_f32_16x16x32_bf16(ax[1][0], Bk[sl][jj], akk[1][0][jj], 0, 0, 0);
            akk[1][1][jj] = __builtin_amdgcn_mfma_f32_16x16x32_bf16(ax[1][1], Bk[sl][jj], akk[1][1][jj], 0, 0, 0);
        }
    }
#undef LOADB

    // ---- phi on q; boundary pprev (row 15 of masked tile = row mbase-1) ----
#pragma unroll
    for (int t2 = 0; t2 < 2; ++t2)
#pragma unroll
        for (int i = 0; i < 2; ++i)
#pragma unroll
            for (int jj = 0; jj < 2; ++jj)
#pragma unroll
                for (int r = 0; r < 4; ++r) aq[t2][i][jj][r] = phi_f(aq[t2][i][jj][r]);
    float pprev[2];
#pragma unroll
    for (int jj = 0; jj < 2; ++jj) {
        float p15 = __shfl(aqp[jj][3], 48 + ln);   // (qd=3,r=3) = row 15, col ln
        pprev[jj] = hasprev ? phi_f(p15) : 0.f;
    }

    // ---- c, cden per (row, head): dpq chain across both tiles ----
    float cc_[2][2][4], cd_[2][2][4];
#pragma unroll
    for (int t2 = 0; t2 < 2; ++t2)
#pragma unroll
        for (int i = 0; i < 2; ++i)
#pragma unroll
            for (int r = 0; r < 4; ++r) { cc_[t2][i][r] = 0.f; cd_[t2][i][r] = 0.f; }
#pragma unroll
    for (int jj = 0; jj < 2; ++jj) {
        float carry = pprev[jj];
#pragma unroll
        for (int t2 = 0; t2 < 2; ++t2)
#pragma unroll
            for (int i = 0; i < 2; ++i) {
                const float p0 = aq[t2][i][jj][0], p1 = aq[t2][i][jj][1];
                const float p2 = aq[t2][i][jj][2], p3 = aq[t2][i][jj][3];
                const float up3 = __shfl_up(p3, 16);
                const float prev0 = (qd == 0) ? carry : up3;
                const float d0 = p0 - prev0, d1 = p1 - p0, d2 = p2 - p1, d3 = p3 - p2;
                cc_[t2][i][0] += d0 * av[t2][i][jj][0]; cd_[t2][i][0] += d0;
                cc_[t2][i][1] += d1 * av[t2][i][jj][1]; cd_[t2][i][1] += d1;
                cc_[t2][i][2] += d2 * av[t2][i][jj][2]; cd_[t2][i][2] += d2;
                cc_[t2][i][3] += d3 * av[t2][i][jj][3]; cd_[t2][i][3] += d3;
                carry = __shfl(p3, ln + 48);
            }
    }
#pragma unroll
    for (int t2 = 0; t2 < 2; ++t2)
#pragma unroll
        for (int i = 0; i < 2; ++i)
#pragma unroll
            for (int r = 0; r < 4; ++r) {
                float x = cc_[t2][i][r];
                x += __shfl_xor(x, 1); x += __shfl_xor(x, 2);
                x += __shfl_xor(x, 4); x += __shfl_xor(x, 8);
                float y = cd_[t2][i][r];
                y += __shfl_xor(y, 1); y += __shfl_xor(y, 2);
                y += __shfl_xor(y, 4); y += __shfl_xor(y, 8);
                if (ln == 0) {
                    scc[t2 * 32 + i * 16 + qd * 4 + r][w] = x;
                    scd[t2 * 32 + i * 16 + qd * 4 + r][w] = y;
                }
            }
    __syncthreads();

    // ---- phi on k; per-tile totals -> global tot (interleaved {num,den}) ----
#pragma unroll
    for (int t2 = 0; t2 < 2; ++t2)
#pragma unroll
        for (int i = 0; i < 2; ++i)
#pragma unroll
            for (int jj = 0; jj < 2; ++jj)
#pragma unroll
                for (int r = 0; r < 4; ++r) akk[t2][i][jj][r] = phi_f(akk[t2][i][jj][r]);
#pragma unroll
    for (int t2 = 0; t2 < 2; ++t2)
#pragma unroll
        for (int jj = 0; jj < 2; ++jj) {
            float tn = 0.f, td = 0.f;
#pragma unroll
            for (int i = 0; i < 2; ++i)
#pragma unroll
                for (int r = 0; r < 4; ++r) {
                    const int row = t2 * 32 + i * 16 + qd * 4 + r;
                    const float pv = akk[t2][i][jj][r];
                    tn += scc[row][w] * pv;
                    td += scd[row][w] * pv;
                }
            tn += __shfl_xor(tn, 16); tn += __shfl_xor(tn, 32);
            td += __shfl_xor(td, 16); td += __shfl_xor(td, 32);
            if (qd == 0) {
                const int d = jj * 16 + ln;
                const size_t bi = ((size_t)(n * 8 + w) * 256 + tile0 + t2) * 64;
                float2 v; v.x = tn; v.y = td;
                *(float2*)&tot[bi + 2 * d] = v;
            }
        }

    // ---- pk -> LDS spk (bf16), consumed in phase B ----
#pragma unroll
    for (int t2 = 0; t2 < 2; ++t2)
#pragma unroll
        for (int i = 0; i < 2; ++i)
#pragma unroll
            for (int jj = 0; jj < 2; ++jj)
#pragma unroll
                for (int r = 0; r < 4; ++r)
                    spk[(t2 * 32 + i * 16 + qd * 4 + r) * 264 + w * 32 + jj * 16 + ln]
                        = f2bf(akk[t2][i][jj][r]);
    __syncthreads();

    // ================= phase B: fused scan (replaces k_scan) ===============
    __threadfence();                 // tot globally visible
    cg::this_grid().sync();

    {
        const int d = lane & 31, g = lane >> 5;   // walker: head w, col d, rows g*32..+31
        const float* tb = tot + (size_t)(n * 8 + w) * 256 * 64 + 2 * d;

        // prefix over tiles [0, tile0): half-range per half-lane, shfl-combined
        float sn0 = 0.f, sn1 = 0.f, sn2 = 0.f, sn3 = 0.f;
        float sn4 = 0.f, sn5 = 0.f, sn6 = 0.f, sn7 = 0.f;
        float sd0 = 0.f, sd1 = 0.f, sd2 = 0.f, sd3 = 0.f;
        float sd4 = 0.f, sd5 = 0.f, sd6 = 0.f, sd7 = 0.f;
        int tt = g * tpair;
        const int te = tt + tpair;
        for (; tt + 7 < te; tt += 8) {
            float2 v0 = *(const float2*)(tb + (size_t)(tt + 0) * 64);
            float2 v1 = *(const float2*)(tb + (size_t)(tt + 1) * 64);
            float2 v2 = *(const float2*)(tb + (size_t)(tt + 2) * 64);
            float2 v3 = *(const float2*)(tb + (size_t)(tt + 3) * 64);
            float2 v4 = *(const float2*)(tb + (size_t)(tt + 4) * 64);
            float2 v5 = *(const float2*)(tb + (size_t)(tt + 5) * 64);
            float2 v6 = *(const float2*)(tb + (size_t)(tt + 6) * 64);
            float2 v7 = *(const float2*)(tb + (size_t)(tt + 7) * 64);
            sn0 += v0.x; sd0 += v0.y; sn1 += v1.x; sd1 += v1.y;
            sn2 += v2.x; sd2 += v2.y; sn3 += v3.x; sd3 += v3.y;
            sn4 += v4.x; sd4 += v4.y; sn5 += v5.x; sd5 += v5.y;
            sn6 += v6.x; sd6 += v6.y; sn7 += v7.x; sd7 += v7.y;
        }
        for (; tt < te; ++tt) {
            float2 v = *(const float2*)(tb + (size_t)tt * 64);
            sn0 += v.x; sd0 += v.y;
        }
        float xn = ((sn0 + sn1) + (sn2 + sn3)) + ((sn4 + sn5) + (sn6 + sn7));
        float xd = ((sd0 + sd1) + (sd2 + sd3)) + ((sd4 + sd5) + (sd6 + sd7));
        xn += __shfl_xor(xn, 32);
        xd += __shfl_xor(xd, 32);
        if (g) {   // rows 32..63 also include this block's first tile
            float2 v = *(const float2*)(tb + (size_t)tile0 * 64);
            xn += v.x; xd += v.y;
        }

        // serial 32-step dual-carry walk from LDS; div off the carried chain
        float rn = xn, rd = xd;
        float* ob = out + ((size_t)n * 8192 + lseg0 + g * 32) * 256 + w * 32 + d;
#pragma unroll
        for (int p = 0; p < 32; ++p) {
            const int m = g * 32 + p;
            const float pkv = bf2f(spk[m * 264 + w * 32 + d]);
            rn += scc[m][w] * pkv;
            rd += scd[m][w] * pkv;
            __builtin_nontemporal_store(rn / rd, &ob[(size_t)p * 256]);
        }
    }
}

extern "C" void kernel_launch(void* const* d_in, const int* in_sizes, int n_in,
                              void* d_out, int out_size, void* d_ws, size_t ws_size,
                              hipStream_t stream)
{
    const float* Y  = (const float*)d_in[0];
    const float* X  = (const float*)d_in[1];
    const float* Wq = (const float*)d_in[2];
    const float* Wk = (const float*)d_in[3];
    const float* Wv = (const float*)d_in[4];
    float* out = (float*)d_out;

    float* ws = (float*)d_ws;
    unsigned short* Wf = (unsigned short*)ws;   // 196608 bf16 = 98304 floats
    float* tot = ws + 98304;                    // 16*256*64 floats (interleaved pairs)

    hipLaunchKernelGGL(k_prepw, dim3(96), dim3(256), 0, stream, Wq, Wk, Wv, Wf);

    void* args[] = {(void*)&Y, (void*)&X, (void*)&Wf, (void*)&tot, (void*)&out};
    hipLaunchCooperativeKernel((const void*)k_gemm, dim3(256), dim3(512),
                               args, 0, stream);
}